// Round 1
// baseline (681.165 us; speedup 1.0000x reference)
//
#include <hip/hip_runtime.h>
#include <stdint.h>

typedef __attribute__((ext_vector_type(8))) short short8;
typedef __attribute__((ext_vector_type(4))) float f32x4;
typedef __attribute__((ext_vector_type(4))) unsigned short ushort4v;

static __device__ __forceinline__ unsigned short f2bf(float f) {
  union { float f; unsigned u; } v; v.f = f;
  unsigned r = v.u + 0x7fffu + ((v.u >> 16) & 1u);
  return (unsigned short)(r >> 16);
}

// ---------------- prep: W -> bf16 MFMA B-fragment layout ----------------
// layout: [c][s][gt(64)][kc(32)][lane(64)][8]  (bf16)
// B-frag (16x16x32): lane l holds col g = gt*16 + (l&15), k = kc*32 + (l>>4)*8 + e
__global__ __launch_bounds__(256) void prep_w(const float* __restrict__ Wa,
                                              const float* __restrict__ Wb,
                                              const float* __restrict__ Wc,
                                              unsigned short* __restrict__ wfrag) {
  int t  = blockIdx.x * 256 + threadIdx.x;   // (c,s,gt,kc,l) packed
  int l  = t & 63;
  int kc = (t >> 6) & 31;
  int gt = (t >> 11) & 63;
  int s  = (t >> 17) & 1;
  int c  = t >> 18;
  const float* W = (c == 0) ? Wa : (c == 1) ? Wb : Wc;
  int g  = gt * 16 + (l & 15);
  int k0 = kc * 32 + ((l >> 4) * 8);
  const float* src = W + (size_t)s * 1024 * 1024 + (size_t)k0 * 1024 + g;
  unsigned short* dst = wfrag + (size_t)t * 8;
#pragma unroll
  for (int e = 0; e < 8; ++e) dst[e] = f2bf(src[(size_t)e * 1024]);
}

// ---------------- prep: softmax A, Aoff frags, diag, BN affine ----------------
__global__ __launch_bounds__(256) void prep_misc(
    const float* e0, const int* a0, const float* b0, const float* g0, const float* be0, const float* rm0, const float* rv0,
    const float* e1, const int* a1, const float* b1, const float* g1, const float* be1, const float* rm1, const float* rv1,
    const float* e2, const int* a2, const float* b2, const float* g2, const float* be2, const float* rm2, const float* rv2,
    unsigned short* __restrict__ aofrag, float* __restrict__ diagA,
    float* __restrict__ scale2, float* __restrict__ shift2) {
  __shared__ float A[64][64];
  int c = blockIdx.x;
  int tid = threadIdx.x;
  const float* ev = (c==0)?e0:(c==1)?e1:e2;
  const int*   ad = (c==0)?a0:(c==1)?a1:a2;
  const float* bb = (c==0)?b0:(c==1)?b1:b2;
  const float* gm = (c==0)?g0:(c==1)?g1:g2;
  const float* bt = (c==0)?be0:(c==1)?be1:be2;
  const float* rm = (c==0)?rm0:(c==1)?rm1:rm2;
  const float* rv = (c==0)?rv0:(c==1)?rv1:rv2;
  if (tid < 64) {
    int n = tid;
    float mx = -3.0e38f;
    for (int m = 0; m < 64; ++m) {
      float lg = (ad[n*64+m] > 0) ? ev[n*64+m] : -9.0e15f;
      A[n][m] = lg; mx = fmaxf(mx, lg);
    }
    float ssum = 0.f;
    for (int m = 0; m < 64; ++m) { float p = __expf(A[n][m] - mx); A[n][m] = p; ssum += p; }
    float inv = 1.f / ssum;
    for (int m = 0; m < 64; ++m) A[n][m] *= inv;
  }
  __syncthreads();
  if (tid < 64) diagA[c*64 + tid] = A[tid][tid];
  // Aoff in MFMA A-fragment layout: [nt(4)][kc(2)][lane(64)][8]
  for (int idx = tid; idx < 4096; idx += 256) {
    int ei = idx & 7;
    int l  = (idx >> 3) & 63;
    int kc = (idx >> 9) & 1;
    int nt = idx >> 10;
    int n = nt*16 + (l & 15);
    int m = kc*32 + ((l >> 4) * 8) + ei;
    float vv = (m == n) ? 0.f : A[n][m];
    aofrag[c*4096 + idx] = f2bf(vv);
  }
  for (int g = tid; g < 1024; g += 256) {
    float sc = gm[g] * rsqrtf(rv[g] + 1e-5f);
    scale2[c*1024 + g] = sc;
    shift2[c*1024 + g] = bt[g] + (bb[g] - rm[g]) * sc;
  }
}

// ---------------- main fused channel kernel ----------------
// CH=0: perm_in (0,1,4,2,3)  x-off = f*32 + i   out-off = g*32 + i      (weight 0.5, write)
// CH=1: identity             x-off = i*1024 + f out-off = i*1024 + g    (weight 0.25, add)
// CH=2: perm_in (0,1,3,2,4)  x-off = (f>>5)*1024 + i*32 + (f&31)
//                            out-off = (g>>5)*1024 + i*32 + (g&31)      (weight 0.25, add)
template<int CH>
__global__ __launch_bounds__(256, 2) void gconv(
    const float* __restrict__ x, const int* __restrict__ idxp,
    const unsigned short* __restrict__ wfrag, const unsigned short* __restrict__ aofrag,
    const float* __restrict__ diagA, const float* __restrict__ scale2,
    const float* __restrict__ shift2, float* __restrict__ out) {
  __shared__ alignas(128) char lds[16384];   // A-tile [64 rows][128 k] bf16, XOR-swizzled; reused as H1b
  int tid  = threadIdx.x;
  int lane = tid & 63;
  int wave = tid >> 6;
  int bid  = blockIdx.x;
  int graph = bid >> 3;             // 0..511
  int gsl   = (bid & 7) * 128;      // feature-slice base
  int b = graph >> 3, v = graph & 7;
  int v2 = idxp[v];
  const float* xb0 = x + (size_t)(b*8 + v)  * 32768;
  const float* xb1 = x + (size_t)(b*8 + v2) * 32768;

  f32x4 acc[2][4][2];
#pragma unroll
  for (int s = 0; s < 2; ++s)
#pragma unroll
    for (int mt = 0; mt < 4; ++mt)
#pragma unroll
      for (int gt = 0; gt < 2; ++gt)
        acc[s][mt][gt] = (f32x4){0.f, 0.f, 0.f, 0.f};

  int gb16 = (gsl >> 4) + wave * 2;   // this wave's global 16-col tile base
  int r0 = lane & 15;
  int kq = (lane >> 4) * 8;

  for (int kt = 0; kt < 8; ++kt) {
    __syncthreads();
    // ---- stage permuted x rows into LDS (bf16, swizzled [row][k] pitch 256B) ----
#pragma unroll
    for (int e2 = 0; e2 < 8; ++e2) {
      int p4 = (tid + e2 * 256) * 4;          // 0..8188, 2 views x 4096 floats
      const float* vb = (p4 < 4096) ? xb0 : xb1;
      int o = p4 & 4095;
      int vbase = (p4 >> 12) * 32;
      if (CH == 0) {
        float4 val = *(const float4*)(vb + kt*4096 + o);
        int i0 = o & 31, fl = o >> 5;
        float vv[4] = {val.x, val.y, val.z, val.w};
#pragma unroll
        for (int j = 0; j < 4; ++j) {
          int row = vbase + i0 + j;
          int byt = (row*256 + fl*2) ^ ((row & 7) << 4);
          *(unsigned short*)(lds + byt) = f2bf(vv[j]);
        }
      } else if (CH == 1) {
        int i = o >> 7, fl = o & 127;
        float4 val = *(const float4*)(vb + i*1024 + kt*128 + fl);
        int row = vbase + i;
        ushort4v w; w.x = f2bf(val.x); w.y = f2bf(val.y); w.z = f2bf(val.z); w.w = f2bf(val.w);
        int byt = (row*256 + fl*2) ^ ((row & 7) << 4);
        *(ushort4v*)(lds + byt) = w;
      } else {
        int jj = o >> 10, i = (o >> 5) & 31, k = o & 31;
        float4 val = *(const float4*)(vb + (kt*4 + jj)*1024 + i*32 + k);
        int row = vbase + i;
        int fl = jj*32 + k;
        ushort4v w; w.x = f2bf(val.x); w.y = f2bf(val.y); w.z = f2bf(val.z); w.w = f2bf(val.w);
        int byt = (row*256 + fl*2) ^ ((row & 7) << 4);
        *(ushort4v*)(lds + byt) = w;
      }
    }
    __syncthreads();
    // ---- MFMA over this K-chunk ----
#pragma unroll
    for (int kk = 0; kk < 4; ++kk) {
      int kcg = kt*4 + kk;
      short8 bf[2][2];
#pragma unroll
      for (int s = 0; s < 2; ++s)
#pragma unroll
        for (int gt = 0; gt < 2; ++gt) {
          size_t off = ((((size_t)(s*64 + gb16 + gt)) * 32 + kcg) * 64 + lane) * 16;
          bf[s][gt] = *(const short8*)((const char*)wfrag + off);
        }
      short8 af[4];
#pragma unroll
      for (int mt = 0; mt < 4; ++mt) {
        int row = mt*16 + r0;
        int byt = (row*256 + (kk*32 + kq)*2) ^ ((row & 7) << 4);
        af[mt] = *(const short8*)(lds + byt);
      }
#pragma unroll
      for (int mt = 0; mt < 4; ++mt)
#pragma unroll
        for (int s = 0; s < 2; ++s)
#pragma unroll
          for (int gt = 0; gt < 2; ++gt)
            acc[s][mt][gt] = __builtin_amdgcn_mfma_f32_16x16x32_bf16(af[mt], bf[s][gt], acc[s][mt][gt], 0, 0, 0);
    }
  }

  // ---- epilogue: aggregation + BN + ReLU + pair-mean + output ----
  __syncthreads();                      // everyone done reading A-tile
  char* hb = lds + wave * 4096;         // per-wave H1b region: [32 g][64 m] bf16, swizzled
  int m0 = (lane >> 4) * 4;
#pragma unroll
  for (int mt = 0; mt < 4; ++mt)
#pragma unroll
    for (int gt = 0; gt < 2; ++gt) {
      int gl = gt*16 + r0;
      int m  = mt*16 + m0;
      ushort4v w;
      w.x = f2bf(acc[1][mt][gt][0]); w.y = f2bf(acc[1][mt][gt][1]);
      w.z = f2bf(acc[1][mt][gt][2]); w.w = f2bf(acc[1][mt][gt][3]);
      int byt = (gl*128 + m*2) ^ ((gl & 7) << 4);
      *(ushort4v*)(hb + byt) = w;
    }
  __syncthreads();

  f32x4 agg[4][2];
#pragma unroll
  for (int nt = 0; nt < 4; ++nt)
#pragma unroll
    for (int gt = 0; gt < 2; ++gt)
      agg[nt][gt] = (f32x4){0.f, 0.f, 0.f, 0.f};

#pragma unroll
  for (int kc = 0; kc < 2; ++kc) {
    short8 hbf[2];
#pragma unroll
    for (int gt = 0; gt < 2; ++gt) {
      int gl = gt*16 + r0;
      int byt = (gl*128 + (kc*32 + kq)*2) ^ ((gl & 7) << 4);
      hbf[gt] = *(const short8*)(hb + byt);
    }
#pragma unroll
    for (int nt = 0; nt < 4; ++nt) {
      short8 aof = *(const short8*)((const char*)aofrag + (size_t)((nt*2 + kc)*64 + lane) * 16);
#pragma unroll
      for (int gt = 0; gt < 2; ++gt)
        agg[nt][gt] = __builtin_amdgcn_mfma_f32_16x16x32_bf16(aof, hbf[gt], agg[nt][gt], 0, 0, 0);
    }
  }

  size_t obase = (size_t)graph * 32768;
#pragma unroll
  for (int gt = 0; gt < 2; ++gt) {
    int g = gsl + wave*32 + gt*16 + r0;
    float sc = scale2[g], sh = shift2[g];
#pragma unroll
    for (int nt = 0; nt < 2; ++nt)
#pragma unroll
      for (int r = 0; r < 4; ++r) {
        int n = nt*16 + m0 + r;           // pair-slice index i in 0..31
        float va = diagA[n]      * acc[0][nt][gt][r]     + agg[nt][gt][r];
        float vb = diagA[n + 32] * acc[0][nt+2][gt][r]   + agg[nt+2][gt][r];
        va = fmaxf(va * sc + sh, 0.f);
        vb = fmaxf(vb * sc + sh, 0.f);
        float res = 0.5f * (va + vb);
        if (CH == 0) {
          out[obase + (size_t)g*32 + n] = 0.5f * res;
        } else if (CH == 1) {
          float* p = out + obase + (size_t)n*1024 + g;
          *p += 0.25f * res;
        } else {
          float* p = out + obase + (size_t)(g >> 5)*1024 + (size_t)n*32 + (g & 31);
          *p += 0.25f * res;
        }
      }
  }
}

extern "C" void kernel_launch(void* const* d_in, const int* in_sizes, int n_in,
                              void* d_out, int out_size, void* d_ws, size_t ws_size,
                              hipStream_t stream) {
  (void)in_sizes; (void)n_in; (void)out_size; (void)ws_size;
  const float* x    = (const float*)d_in[0];
  const int*   idx  = (const int*)d_in[1];
  const int*   adj1 = (const int*)d_in[2];
  const int*   adj2 = (const int*)d_in[3];
  const float *W[3], *e[3], *bb[3], *gm[3], *bt[3], *rm[3], *rv[3];
  for (int c = 0; c < 3; ++c) {
    int base = 4 + c*7;
    W[c]  = (const float*)d_in[base + 0];
    e[c]  = (const float*)d_in[base + 1];
    bb[c] = (const float*)d_in[base + 2];
    gm[c] = (const float*)d_in[base + 3];
    bt[c] = (const float*)d_in[base + 4];
    rm[c] = (const float*)d_in[base + 5];
    rv[c] = (const float*)d_in[base + 6];
  }
  char* ws = (char*)d_ws;
  unsigned short* wfrag  = (unsigned short*)ws;                    // 3 * 2,097,152 bf16 = 12 MB
  unsigned short* aofrag = (unsigned short*)(ws + 12582912);       // 3 * 4096 bf16
  float* diagA  = (float*)(ws + 12607488);                         // 3 * 64 f32
  float* scale2 = (float*)(ws + 12608256);                         // 3 * 1024 f32
  float* shift2 = (float*)(ws + 12620544);                         // 3 * 1024 f32

  prep_w<<<3072, 256, 0, stream>>>(W[0], W[1], W[2], wfrag);
  prep_misc<<<3, 256, 0, stream>>>(
      e[0], adj1, bb[0], gm[0], bt[0], rm[0], rv[0],
      e[1], adj2, bb[1], gm[1], bt[1], rm[1], rv[1],
      e[2], adj2, bb[2], gm[2], bt[2], rm[2], rv[2],
      aofrag, diagA, scale2, shift2);

  float* out = (float*)d_out;
  gconv<0><<<4096, 256, 0, stream>>>(x, idx, wfrag,           aofrag,        diagA,       scale2,        shift2,        out);
  gconv<1><<<4096, 256, 0, stream>>>(x, idx, wfrag + 2097152, aofrag + 4096, diagA + 64,  scale2 + 1024, shift2 + 1024, out);
  gconv<2><<<4096, 256, 0, stream>>>(x, idx, wfrag + 4194304, aofrag + 8192, diagA + 128, scale2 + 2048, shift2 + 2048, out);
}